// Round 1
// baseline (229.964 us; speedup 1.0000x reference)
//
#include <hip/hip_runtime.h>
#include <hip/hip_bf16.h>

#define NUM_D1 270
#define NUM_B  128
#define NUM_C  273
#define NUM_T  1024
#define KL     1024      // K*K = 32*32
#define TW     320       // trig table padded width (covers 5*64 lanes)
#define CP     288       // padded C (9 * 32)
#define JP     272       // padded D1 (17 * 16)
#define LDA    40        // LDS row stride in bf16 elems (80 B, 16B-aligned, conflict-reducing)

typedef float f32x4 __attribute__((ext_vector_type(4)));
typedef __bf16 bf16x8 __attribute__((ext_vector_type(8)));

// ---- ws layout (bytes) ----
// cosT: [KL][TW] f32   @ 0          (1,310,720)
// sinT: [KL][TW] f32   @ 1,310,720  (1,310,720)
// a:    [JP][CP] f32   @ 2,621,440  (313,344)
// wg:   [JP][CP] bf16  @ 2,934,784  (156,672)   total ~3.1 MB

static __device__ __forceinline__ unsigned short f2bf(float f) {
  unsigned u = __float_as_uint(f);
  unsigned r = (u + 0x7fffu + ((u >> 16) & 1u)) >> 16;   // round-to-nearest-even
  return (unsigned short)r;
}

// Kernel 0: trig tables cos/sin(2*pi*(k*x + l*y)) for all (kl, c)
__global__ __launch_bounds__(256) void k_trig(const float* __restrict__ loc,
                                              float* __restrict__ cosT,
                                              float* __restrict__ sinT) {
  int idx = blockIdx.x * 256 + threadIdx.x;   // 0 .. 1024*320-1
  int kl = idx / TW;
  int c  = idx - kl * TW;
  float cv = 0.f, sv = 0.f;
  if (c < NUM_C) {
    float x = loc[2 * c], y = loc[2 * c + 1];
    float kf = (float)(kl >> 5), lf = (float)(kl & 31);
    float ph = 6.283185307179586f * (kf * x + lf * y);
    sincosf(ph, &sv, &cv);
  }
  cosT[idx] = cv;
  sinT[idx] = sv;
}

// Kernel 1: a[j,c] = sum_kl z_re[j,kl]*cos[kl,c] + z_im[j,kl]*sin[kl,c]
__global__ __launch_bounds__(256) void k_agemm(const float* __restrict__ z_re,
                                               const float* __restrict__ z_im,
                                               const float* __restrict__ cosT,
                                               const float* __restrict__ sinT,
                                               float* __restrict__ a) {
  int jb = blockIdx.x;             // 0..33
  int cb = blockIdx.y;             // 0..4
  int lane = threadIdx.x & 63;
  int grp  = threadIdx.x >> 6;     // 0..3
  int c = cb * 64 + lane;          // < 320, in-bounds of padded table
  int j0 = jb * 8 + grp;           // <= 267, always valid
  int j1 = j0 + 4;                 // <= 271, may exceed 269
  int je1 = (j1 < NUM_D1) ? j1 : 0;
  const float* zr0 = z_re + (size_t)j0 * KL;
  const float* zi0 = z_im + (size_t)j0 * KL;
  const float* zr1 = z_re + (size_t)je1 * KL;
  const float* zi1 = z_im + (size_t)je1 * KL;
  float a0 = 0.f, a1 = 0.f;
  #pragma unroll 4
  for (int kk = 0; kk < KL; ++kk) {
    float cv = cosT[kk * TW + c];
    float sv = sinT[kk * TW + c];
    a0 = fmaf(zr0[kk], cv, a0);
    a0 = fmaf(zi0[kk], sv, a0);
    a1 = fmaf(zr1[kk], cv, a1);
    a1 = fmaf(zi1[kk], sv, a1);
  }
  if (c < NUM_C) {
    a[j0 * CP + c] = a0;
    if (j1 < NUM_D1) a[j1 * CP + c] = a1;
  }
}

// Kernel 2: w[j,:] = softmax_c(a[j,:]) -> bf16, zero-padded to [JP][CP]
__global__ __launch_bounds__(64) void k_softmax(const float* __restrict__ a,
                                                unsigned short* __restrict__ wg) {
  int j = blockIdx.x;      // 0..271
  int lane = threadIdx.x;  // 0..63
  if (j >= NUM_D1) {
    for (int c = lane; c < CP; c += 64) wg[j * CP + c] = 0;
    return;
  }
  float e[5];
  float s = 0.f;
  #pragma unroll
  for (int q = 0; q < 5; ++q) {
    int c = q * 64 + lane;
    float v = 0.f;
    if (c < NUM_C) v = expf(a[j * CP + c]);
    e[q] = v;
    s += v;
  }
  #pragma unroll
  for (int o = 32; o > 0; o >>= 1) s += __shfl_xor(s, o, 64);
  float inv = 1.0f / s;
  #pragma unroll
  for (int q = 0; q < 5; ++q) {
    int c = q * 64 + lane;
    if (c < CP) wg[j * CP + c] = (c < NUM_C) ? f2bf(e[q] * inv) : (unsigned short)0;
  }
}

// Kernel 3: out[b,j,t] = sum_c w[j,c] * X[b,c,t]  (bf16 MFMA, fp32 accum)
__global__ __launch_bounds__(256) void k_out(const float* __restrict__ X,
                                             const unsigned short* __restrict__ wg,
                                             float* __restrict__ out) {
  __shared__ unsigned short Al[JP * LDA];   // w tile   [272][LDA]
  __shared__ unsigned short Xl[64 * LDA];   // X^T tile [64 t][LDA c]
  int tid = threadIdx.x;
  int wv = tid >> 6, lane = tid & 63;
  int rlo = lane & 15, kg = lane >> 4;
  int t0 = blockIdx.x * 64;
  int b  = blockIdx.y;
  const float* Xb = X + (size_t)b * NUM_C * NUM_T;

  f32x4 acc[5][4];
  #pragma unroll
  for (int m = 0; m < 5; ++m)
    #pragma unroll
    for (int tt = 0; tt < 4; ++tt)
      #pragma unroll
      for (int r = 0; r < 4; ++r) acc[m][tt][r] = 0.f;

  for (int ks = 0; ks < 9; ++ks) {
    int c0 = ks * 32;
    if (ks) __syncthreads();
    // stage A: rows 0..271, cols c0..c0+31 (each row = 4 x 16B chunks)
    #pragma unroll
    for (int it = 0; it < 5; ++it) {
      int ch = tid + it * 256;
      if (ch < JP * 4) {
        int row = ch >> 2, sub = ch & 3;
        uint4 v = *(const uint4*)((const char*)wg + (size_t)row * (CP * 2) + c0 * 2 + sub * 16);
        *(uint4*)((char*)Al + row * (LDA * 2) + sub * 16) = v;
      }
    }
    // stage X^T: thread (wave wv, lane) loads 8 c's at t = t0+lane, converts to bf16
    {
      int t = lane;
      int cg = wv;
      unsigned pk0, pk1, pk2, pk3;
      {
        int ca = c0 + cg * 8;
        float f0 = (ca + 0 < NUM_C) ? Xb[(size_t)(ca + 0) * NUM_T + t0 + t] : 0.f;
        float f1 = (ca + 1 < NUM_C) ? Xb[(size_t)(ca + 1) * NUM_T + t0 + t] : 0.f;
        float f2 = (ca + 2 < NUM_C) ? Xb[(size_t)(ca + 2) * NUM_T + t0 + t] : 0.f;
        float f3 = (ca + 3 < NUM_C) ? Xb[(size_t)(ca + 3) * NUM_T + t0 + t] : 0.f;
        float f4 = (ca + 4 < NUM_C) ? Xb[(size_t)(ca + 4) * NUM_T + t0 + t] : 0.f;
        float f5 = (ca + 5 < NUM_C) ? Xb[(size_t)(ca + 5) * NUM_T + t0 + t] : 0.f;
        float f6 = (ca + 6 < NUM_C) ? Xb[(size_t)(ca + 6) * NUM_T + t0 + t] : 0.f;
        float f7 = (ca + 7 < NUM_C) ? Xb[(size_t)(ca + 7) * NUM_T + t0 + t] : 0.f;
        pk0 = (unsigned)f2bf(f0) | ((unsigned)f2bf(f1) << 16);
        pk1 = (unsigned)f2bf(f2) | ((unsigned)f2bf(f3) << 16);
        pk2 = (unsigned)f2bf(f4) | ((unsigned)f2bf(f5) << 16);
        pk3 = (unsigned)f2bf(f6) | ((unsigned)f2bf(f7) << 16);
      }
      uint4 upk;
      upk.x = pk0; upk.y = pk1; upk.z = pk2; upk.w = pk3;
      *(uint4*)((char*)Xl + t * (LDA * 2) + cg * 16) = upk;
    }
    __syncthreads();

    bf16x8 bfr[4];
    #pragma unroll
    for (int tt = 0; tt < 4; ++tt)
      bfr[tt] = *(const bf16x8*)((const char*)Xl + (tt * 16 + rlo) * (LDA * 2) + kg * 16);

    #pragma unroll
    for (int m = 0; m < 5; ++m) {
      int jt = wv + 4 * m;
      if (jt < 17) {
        bf16x8 afr = *(const bf16x8*)((const char*)Al + (jt * 16 + rlo) * (LDA * 2) + kg * 16);
        #pragma unroll
        for (int tt = 0; tt < 4; ++tt)
          acc[m][tt] = __builtin_amdgcn_mfma_f32_16x16x32_bf16(afr, bfr[tt], acc[m][tt], 0, 0, 0);
      }
    }
  }

  // epilogue: C layout col = lane&15 (t), row = (lane>>4)*4 + r (j within tile)
  #pragma unroll
  for (int m = 0; m < 5; ++m) {
    int jt = wv + 4 * m;
    if (jt >= 17) continue;
    #pragma unroll
    for (int tt = 0; tt < 4; ++tt) {
      #pragma unroll
      for (int r = 0; r < 4; ++r) {
        int j = jt * 16 + kg * 4 + r;
        if (j < NUM_D1)
          out[((size_t)b * NUM_D1 + j) * NUM_T + t0 + tt * 16 + rlo] = acc[m][tt][r];
      }
    }
  }
}

extern "C" void kernel_launch(void* const* d_in, const int* in_sizes, int n_in,
                              void* d_out, int out_size, void* d_ws, size_t ws_size,
                              hipStream_t stream) {
  const float* X   = (const float*)d_in[0];
  const float* loc = (const float*)d_in[1];
  const float* zre = (const float*)d_in[2];
  const float* zim = (const float*)d_in[3];
  float* out = (float*)d_out;
  char* ws = (char*)d_ws;
  float* cosT = (float*)(ws);
  float* sinT = (float*)(ws + 1310720);
  float* a    = (float*)(ws + 2621440);
  unsigned short* wgp = (unsigned short*)(ws + 2934784);

  hipLaunchKernelGGL(k_trig,    dim3(1280),    dim3(256), 0, stream, loc, cosT, sinT);
  hipLaunchKernelGGL(k_agemm,   dim3(34, 5),   dim3(256), 0, stream, zre, zim, cosT, sinT, a);
  hipLaunchKernelGGL(k_softmax, dim3(272),     dim3(64),  0, stream, a, wgp);
  hipLaunchKernelGGL(k_out,     dim3(16, 128), dim3(256), 0, stream, X, wgp, out);
}

// Round 3
// 167.407 us; speedup vs baseline: 1.3737x; 1.3737x over previous
//
#include <hip/hip_runtime.h>
#include <hip/hip_bf16.h>

#define NUM_D1 270
#define NUM_B  128
#define NUM_C  273
#define NUM_T  1024
#define KL     1024      // K*K = 32*32
#define TW     320       // trig table padded width
#define CP     288       // padded C (9 * 32)
#define JP     272       // padded D1 (17 * 16)
#define XLD    296       // Xl row stride in bf16 elems (592 B, 16B mult)

typedef float f32x4 __attribute__((ext_vector_type(4)));
typedef __bf16 bf16x8 __attribute__((ext_vector_type(8)));

// ---- ws layout (bytes) ----
// cosT: [KL][TW] f32   @ 0          (1,310,720)
// sinT: [KL][TW] f32   @ 1,310,720  (1,310,720)
// a:    [JP][CP] f32   @ 2,621,440  (313,344)
// wg:   [JP][CP] bf16  @ 2,934,784  (156,672)   total ~3.1 MB

static __device__ __forceinline__ unsigned short f2bf(float f) {
  unsigned u = __float_as_uint(f);
  unsigned r = (u + 0x7fffu + ((u >> 16) & 1u)) >> 16;   // RNE
  return (unsigned short)r;
}

// Kernel 0: trig tables cos/sin(2*pi*(k*x + l*y)) for all (kl, c)
__global__ __launch_bounds__(256) void k_trig(const float* __restrict__ loc,
                                              float* __restrict__ cosT,
                                              float* __restrict__ sinT) {
  int idx = blockIdx.x * 256 + threadIdx.x;   // 0 .. 1024*320-1
  int kl = idx / TW;
  int c  = idx - kl * TW;
  float cv = 0.f, sv = 0.f;
  if (c < NUM_C) {
    float x = loc[2 * c], y = loc[2 * c + 1];
    float kf = (float)(kl >> 5), lf = (float)(kl & 31);
    float ph = 6.283185307179586f * (kf * x + lf * y);
    sincosf(ph, &sv, &cv);
  }
  cosT[idx] = cv;
  sinT[idx] = sv;
}

// Kernel 1: a[j,c] = sum_kl z_re[j,kl]*cos[kl,c] + z_im[j,kl]*sin[kl,c]
// block 1024 thr = 16 groups of 64 lanes: group g = (p in 0..1) x (q in 0..7)
// thread: j_a = jb*4+p, j_b = j_a+2; kl range [q*128, q*128+128); LDS-reduce over q.
__global__ __launch_bounds__(1024) void k_agemm(const float* __restrict__ z_re,
                                                const float* __restrict__ z_im,
                                                const float* __restrict__ cosT,
                                                const float* __restrict__ sinT,
                                                float* __restrict__ a) {
  __shared__ float sm[4][8][64];
  int tid = threadIdx.x;
  int lane = tid & 63;
  int g = tid >> 6;            // 0..15
  int p = g >> 3;              // 0..1
  int q = g & 7;               // 0..7
  int jb = blockIdx.x;         // 0..67
  int cb = blockIdx.y;         // 0..4
  int c = cb * 64 + lane;      // < 320, in-bounds of padded table
  int j_a = jb * 4 + p;        // <= 269
  int j_b = j_a + 2;           // <= 271
  int jeb = (j_b < NUM_D1) ? j_b : 0;
  const float* zr0 = z_re + (size_t)j_a * KL;
  const float* zi0 = z_im + (size_t)j_a * KL;
  const float* zr1 = z_re + (size_t)jeb * KL;
  const float* zi1 = z_im + (size_t)jeb * KL;
  float a0 = 0.f, a1 = 0.f;
  int k0 = q * 128;
  #pragma unroll 4
  for (int kk = k0; kk < k0 + 128; ++kk) {
    float cv = cosT[kk * TW + c];
    float sv = sinT[kk * TW + c];
    a0 = fmaf(zr0[kk], cv, a0);
    a0 = fmaf(zi0[kk], sv, a0);
    a1 = fmaf(zr1[kk], cv, a1);
    a1 = fmaf(zi1[kk], sv, a1);
  }
  sm[p][q][lane] = a0;
  sm[p + 2][q][lane] = a1;
  __syncthreads();
  if (tid < 256) {
    int jl = tid >> 6;          // 0..3
    int l2 = tid & 63;
    int j = jb * 4 + jl;
    int c2 = cb * 64 + l2;
    float s = 0.f;
    #pragma unroll
    for (int qq = 0; qq < 8; ++qq) s += sm[jl][qq][l2];
    if (j < NUM_D1 && c2 < NUM_C) a[j * CP + c2] = s;
  }
}

// Kernel 2: w[j,:] = softmax_c(a[j,:]) -> bf16, zero-padded to [JP][CP]; 4 rows/block
__global__ __launch_bounds__(256) void k_softmax(const float* __restrict__ a,
                                                 unsigned short* __restrict__ wg) {
  int wv = threadIdx.x >> 6;
  int lane = threadIdx.x & 63;
  int j = blockIdx.x * 4 + wv;   // < 272
  if (j >= NUM_D1) {
    for (int c = lane; c < CP; c += 64) wg[j * CP + c] = 0;
    return;
  }
  float e[5];
  float s = 0.f;
  #pragma unroll
  for (int qq = 0; qq < 5; ++qq) {
    int c = qq * 64 + lane;
    float v = 0.f;
    if (c < NUM_C) v = expf(a[j * CP + c]);
    e[qq] = v;
    s += v;
  }
  #pragma unroll
  for (int o = 32; o > 0; o >>= 1) s += __shfl_xor(s, o, 64);
  float inv = 1.0f / s;
  #pragma unroll
  for (int qq = 0; qq < 5; ++qq) {
    int c = qq * 64 + lane;
    if (c < CP) wg[j * CP + c] = (c < NUM_C) ? f2bf(e[qq] * inv) : (unsigned short)0;
  }
}

// Kernel 3: out[b,j,t] = sum_c w[j,c] * X[b,c,t]  (bf16 MFMA, fp32 accum)
// One barrier: stage full X^T tile [64 t][288 c] bf16 (XOR-swizzled cols, zero-padded),
// then waves free-run over j-tiles x K with A-frags read straight from global w (L2-hot).
__global__ __launch_bounds__(256, 3) void k_out(const float* __restrict__ X,
                                                const unsigned short* __restrict__ wg,
                                                float* __restrict__ out) {
  __shared__ unsigned short Xl[64 * XLD];   // 37,888 B
  int tid = threadIdx.x;
  int wv = tid >> 6, lane = tid & 63;
  int rlo = lane & 15, kg = lane >> 4;
  int t0 = blockIdx.x * 64;
  int b  = blockIdx.y;
  const float* Xb = X + (size_t)b * (NUM_C * NUM_T);

  // ---- stage: X[b][c][t0+lane] -> Xl[t=lane][c], bf16, swizzled; zero-fill c>=NUM_C ----
  {
    int swz = ((lane >> 3) & 3) << 4;                  // 16B-granular XOR per t
    char* rowp = (char*)Xl + lane * (XLD * 2);
    #pragma unroll 4
    for (int i = 0; i < 72; ++i) {
      int c = wv + 4 * i;                              // covers 0..287 exactly
      float f = (c < NUM_C) ? Xb[(size_t)c * NUM_T + t0 + lane] : 0.f;
      *(unsigned short*)(rowp + ((2 * c) ^ swz)) = f2bf(f);
    }
  }

  f32x4 acc[5][4];
  #pragma unroll
  for (int m = 0; m < 5; ++m)
    #pragma unroll
    for (int tt = 0; tt < 4; ++tt)
      #pragma unroll
      for (int r = 0; r < 4; ++r) acc[m][tt][r] = 0.f;

  __syncthreads();

  for (int ks = 0; ks < 9; ++ks) {
    // B fragments: Xl[t = tt*16+rlo][c = ks*32 + kg*8 .. +7]
    bf16x8 bfr[4];
    #pragma unroll
    for (int tt = 0; tt < 4; ++tt) {
      int row = tt * 16 + rlo;
      int colb = (ks * 64 + kg * 16) ^ (((row >> 3) & 3) << 4);
      bfr[tt] = *(const bf16x8*)((const char*)Xl + row * (XLD * 2) + colb);
    }
    #pragma unroll
    for (int m = 0; m < 5; ++m) {
      int jt = wv + 4 * m;
      if (jt < 17) {
        // A fragment straight from global (L2-resident): row jt*16+rlo, k = ks*32+kg*8
        bf16x8 afr = *(const bf16x8*)((const char*)wg +
                       ((size_t)(jt * 16 + rlo) * CP + ks * 32 + kg * 8) * 2);
        #pragma unroll
        for (int tt = 0; tt < 4; ++tt)
          acc[m][tt] = __builtin_amdgcn_mfma_f32_16x16x32_bf16(afr, bfr[tt], acc[m][tt], 0, 0, 0);
      }
    }
  }

  // epilogue: C layout col = lane&15 (t), row = (lane>>4)*4 + r (j within tile)
  #pragma unroll
  for (int m = 0; m < 5; ++m) {
    int jt = wv + 4 * m;
    if (jt >= 17) continue;
    #pragma unroll
    for (int tt = 0; tt < 4; ++tt) {
      #pragma unroll
      for (int r = 0; r < 4; ++r) {
        int j = jt * 16 + kg * 4 + r;
        if (j < NUM_D1)
          out[((size_t)b * NUM_D1 + j) * NUM_T + t0 + tt * 16 + rlo] = acc[m][tt][r];
      }
    }
  }
}

extern "C" void kernel_launch(void* const* d_in, const int* in_sizes, int n_in,
                              void* d_out, int out_size, void* d_ws, size_t ws_size,
                              hipStream_t stream) {
  const float* X   = (const float*)d_in[0];
  const float* loc = (const float*)d_in[1];
  const float* zre = (const float*)d_in[2];
  const float* zim = (const float*)d_in[3];
  float* out = (float*)d_out;
  char* ws = (char*)d_ws;
  float* cosT = (float*)(ws);
  float* sinT = (float*)(ws + 1310720);
  float* a    = (float*)(ws + 2621440);
  unsigned short* wgp = (unsigned short*)(ws + 2934784);

  hipLaunchKernelGGL(k_trig,    dim3(1280),    dim3(256),  0, stream, loc, cosT, sinT);
  hipLaunchKernelGGL(k_agemm,   dim3(68, 5),   dim3(1024), 0, stream, zre, zim, cosT, sinT, a);
  hipLaunchKernelGGL(k_softmax, dim3(68),      dim3(256),  0, stream, a, wgp);
  hipLaunchKernelGGL(k_out,     dim3(16, 128), dim3(256),  0, stream, X, wgp, out);
}

// Round 4
// 129.093 us; speedup vs baseline: 1.7814x; 1.2968x over previous
//
#include <hip/hip_runtime.h>
#include <hip/hip_bf16.h>

#define NUM_D1 270
#define NUM_B  128
#define NUM_C  273
#define NUM_T  1024
#define KL     1024      // K*K = 32*32
#define TW     320       // trig table padded width
#define CP     288       // padded C for a[] (9 * 32)
#define CW     296       // wg row stride in elems (592 B = 148 dw == 20 mod 32 -> conflict-free b128)
#define JW     288       // wg rows (18 * 16), zero-padded past 270

// k_out2 LDS layout (bytes)
#define XP_OFF 0         // [128 t][256 c] bf16, row 512 B, XOR-swizzled
#define XQ_OFF 65536     // [128 t][32 c]  bf16, row 64 B, XOR-swizzled
#define WT_OFF 73728     // [144 j][296 c] bf16, row 592 B, linear
#define LDS_TOTAL 158976

typedef float f32x4 __attribute__((ext_vector_type(4)));
typedef __bf16 bf16x8 __attribute__((ext_vector_type(8)));

static __device__ __forceinline__ unsigned short f2bf(float f) {
  unsigned u = __float_as_uint(f);
  unsigned r = (u + 0x7fffu + ((u >> 16) & 1u)) >> 16;   // RNE
  return (unsigned short)r;
}

// Kernel 0: trig tables cos/sin(2*pi*(k*x + l*y)) for all (kl, c)
__global__ __launch_bounds__(256) void k_trig(const float* __restrict__ loc,
                                              float* __restrict__ cosT,
                                              float* __restrict__ sinT) {
  int idx = blockIdx.x * 256 + threadIdx.x;   // 0 .. 1024*320-1
  int kl = idx / TW;
  int c  = idx - kl * TW;
  float cv = 0.f, sv = 0.f;
  if (c < NUM_C) {
    float x = loc[2 * c], y = loc[2 * c + 1];
    float kf = (float)(kl >> 5), lf = (float)(kl & 31);
    float ph = 6.283185307179586f * (kf * x + lf * y);
    sincosf(ph, &sv, &cv);
  }
  cosT[idx] = cv;
  sinT[idx] = sv;
}

// Kernel 1: a[j,c] = sum_kl z_re[j,kl]*cos[kl,c] + z_im[j,kl]*sin[kl,c]
__global__ __launch_bounds__(1024) void k_agemm(const float* __restrict__ z_re,
                                                const float* __restrict__ z_im,
                                                const float* __restrict__ cosT,
                                                const float* __restrict__ sinT,
                                                float* __restrict__ a) {
  __shared__ float sm[4][8][64];
  int tid = threadIdx.x;
  int lane = tid & 63;
  int g = tid >> 6;            // 0..15
  int p = g >> 3;              // 0..1
  int q = g & 7;               // 0..7
  int jb = blockIdx.x;         // 0..67
  int cb = blockIdx.y;         // 0..4
  int c = cb * 64 + lane;      // < 320, in-bounds of padded table
  int j_a = jb * 4 + p;        // <= 269
  int j_b = j_a + 2;           // <= 271
  int jeb = (j_b < NUM_D1) ? j_b : 0;
  const float* zr0 = z_re + (size_t)j_a * KL;
  const float* zi0 = z_im + (size_t)j_a * KL;
  const float* zr1 = z_re + (size_t)jeb * KL;
  const float* zi1 = z_im + (size_t)jeb * KL;
  float a0 = 0.f, a1 = 0.f;
  int k0 = q * 128;
  #pragma unroll 4
  for (int kk = k0; kk < k0 + 128; ++kk) {
    float cv = cosT[kk * TW + c];
    float sv = sinT[kk * TW + c];
    a0 = fmaf(zr0[kk], cv, a0);
    a0 = fmaf(zi0[kk], sv, a0);
    a1 = fmaf(zr1[kk], cv, a1);
    a1 = fmaf(zi1[kk], sv, a1);
  }
  sm[p][q][lane] = a0;
  sm[p + 2][q][lane] = a1;
  __syncthreads();
  if (tid < 256) {
    int jl = tid >> 6;          // 0..3
    int l2 = tid & 63;
    int j = jb * 4 + jl;
    int c2 = cb * 64 + l2;
    float s = 0.f;
    #pragma unroll
    for (int qq = 0; qq < 8; ++qq) s += sm[jl][qq][l2];
    if (j < NUM_D1 && c2 < NUM_C) a[j * CP + c2] = s;
  }
}

// Kernel 2: w[j,:] = softmax_c(a[j,:]) -> bf16 into wg[JW=288 rows][CW=296 stride], zero-padded
__global__ __launch_bounds__(256) void k_softmax(const float* __restrict__ a,
                                                 unsigned short* __restrict__ wg) {
  int wv = threadIdx.x >> 6;
  int lane = threadIdx.x & 63;
  int j = blockIdx.x * 4 + wv;   // < 288 (grid 72)
  if (j >= NUM_D1) {
    for (int c = lane; c < CW; c += 64) wg[j * CW + c] = 0;
    return;
  }
  float e[5];
  float s = 0.f;
  #pragma unroll
  for (int qq = 0; qq < 5; ++qq) {
    int c = qq * 64 + lane;
    float v = 0.f;
    if (c < NUM_C) v = expf(a[j * CP + c]);
    e[qq] = v;
    s += v;
  }
  #pragma unroll
  for (int o = 32; o > 0; o >>= 1) s += __shfl_xor(s, o, 64);
  float inv = 1.0f / s;
  #pragma unroll
  for (int qq = 0; qq < 5; ++qq) {
    int c = qq * 64 + lane;
    if (c < CW) wg[j * CW + c] = (c < NUM_C) ? f2bf(e[qq] * inv) : (unsigned short)0;
  }
}

// Kernel 3: out[b,j,t] = sum_c w[j,c] * X[b,c,t]  (bf16 MFMA, fp32 accum)
// Block = (t-tile 128) x b, 1024 thr / 16 waves, grid (8,128), 1 block/CU.
// Stage X^T (bf16, swizzled) once; stage w in two 144-row halves into LDS; B-frags in regs.
__global__ __launch_bounds__(1024) void k_out2(const float* __restrict__ X,
                                               const unsigned short* __restrict__ wg,
                                               float* __restrict__ out) {
  extern __shared__ char lds[];
  char* XPb = lds + XP_OFF;
  char* XQb = lds + XQ_OFF;
  char* WTb = lds + WT_OFF;

  int tid = threadIdx.x;
  int wv = tid >> 6, lane = tid & 63;
  int rlo = lane & 15, kg = lane >> 4;
  int tt = wv >> 1;        // 0..7  (16-t slice)
  int jq = wv & 1;         // jt-quarter within the 144-row half: 0 -> jt16 0..4, 1 -> 5..8
  int t0 = blockIdx.x * 128;
  int b  = blockIdx.y;
  const float* Xb = X + (size_t)b * (NUM_C * NUM_T);

  // ---- stage X^T: 4x4 f32 blocks, float4 loads, b64 swizzled LDS writes ----
  #pragma unroll
  for (int it = 0; it < 3; ++it) {
    int idx = tid + it * 1024;
    int t4 = idx & 31;            // 0..31
    int c4 = idx >> 5;            // 0..95, guard < 72
    if (c4 < 72) {
      float v[4][4];
      #pragma unroll
      for (int e = 0; e < 4; ++e) {
        int c = c4 * 4 + e;
        if (c < NUM_C) {
          f32x4 ld = *(const f32x4*)(Xb + (size_t)c * NUM_T + t0 + t4 * 4);
          v[e][0] = ld[0]; v[e][1] = ld[1]; v[e][2] = ld[2]; v[e][3] = ld[3];
        } else {
          v[e][0] = v[e][1] = v[e][2] = v[e][3] = 0.f;
        }
      }
      #pragma unroll
      for (int f = 0; f < 4; ++f) {
        int t = t4 * 4 + f;
        ushort4 pk;
        pk.x = f2bf(v[0][f]); pk.y = f2bf(v[1][f]);
        pk.z = f2bf(v[2][f]); pk.w = f2bf(v[3][f]);
        if (c4 < 64) {
          int sw = ((t >> 2) & 7) << 4;
          *(ushort4*)(XPb + t * 512 + ((c4 * 8) ^ sw)) = pk;
        } else {
          int sw = ((t >> 2) & 3) << 4;
          *(ushort4*)(XQb + t * 64 + (((c4 - 64) * 8) ^ sw)) = pk;
        }
      }
    }
  }

  // ---- stage W half 0 (rows 0..143) : linear 85,248 B copy ----
  {
    const char* src = (const char*)wg;   // half 0 at offset 0
    #pragma unroll
    for (int it = 0; it < 6; ++it) {
      int off = (tid + it * 1024) * 16;
      if (off < 144 * CW * 2)
        *(uint4*)(WTb + off) = *(const uint4*)(src + off);
    }
  }

  __syncthreads();

  // ---- B fragments once (X^T LDS is stable across both halves) ----
  bf16x8 bfr[9];
  {
    int t = tt * 16 + rlo;
    int swp = ((t >> 2) & 7) << 4;
    #pragma unroll
    for (int ks = 0; ks < 8; ++ks)
      bfr[ks] = *(const bf16x8*)(XPb + t * 512 + ((ks * 64 + kg * 16) ^ swp));
    int swq = ((t >> 2) & 3) << 4;
    bfr[8] = *(const bf16x8*)(XQb + t * 64 + ((kg * 16) ^ swq));
  }

  #pragma unroll
  for (int jh = 0; jh < 2; ++jh) {
    if (jh == 1) {
      __syncthreads();   // all waves done reading WT half 0
      const char* src = (const char*)wg + (size_t)144 * CW * 2;
      #pragma unroll
      for (int it = 0; it < 6; ++it) {
        int off = (tid + it * 1024) * 16;
        if (off < 144 * CW * 2)
          *(uint4*)(WTb + off) = *(const uint4*)(src + off);
      }
      __syncthreads();
    }

    int njj = jq ? 4 : 5;
    f32x4 acc[5];
    #pragma unroll
    for (int jj = 0; jj < 5; ++jj)
      #pragma unroll
      for (int r = 0; r < 4; ++r) acc[jj][r] = 0.f;

    #pragma unroll
    for (int jj = 0; jj < 5; ++jj) {
      if (jj < njj) {
        int jt16 = jq * 5 + jj;
        const char* arow = WTb + ((size_t)(jt16 * 16 + rlo) * CW + kg * 8) * 2;
        #pragma unroll
        for (int ks = 0; ks < 9; ++ks) {
          bf16x8 afr = *(const bf16x8*)(arow + ks * 64);
          acc[jj] = __builtin_amdgcn_mfma_f32_16x16x32_bf16(afr, bfr[ks], acc[jj], 0, 0, 0);
        }
      }
    }

    // store: C layout col = lane&15 (t), row = kg*4 + r (j within 16-tile)
    #pragma unroll
    for (int jj = 0; jj < 5; ++jj) {
      if (jj < njj) {
        int jt16 = jq * 5 + jj;
        #pragma unroll
        for (int r = 0; r < 4; ++r) {
          int j = jh * 144 + jt16 * 16 + kg * 4 + r;
          if (j < NUM_D1)
            out[((size_t)b * NUM_D1 + j) * NUM_T + t0 + tt * 16 + rlo] = acc[jj][r];
        }
      }
    }
  }
}

extern "C" void kernel_launch(void* const* d_in, const int* in_sizes, int n_in,
                              void* d_out, int out_size, void* d_ws, size_t ws_size,
                              hipStream_t stream) {
  const float* X   = (const float*)d_in[0];
  const float* loc = (const float*)d_in[1];
  const float* zre = (const float*)d_in[2];
  const float* zim = (const float*)d_in[3];
  float* out = (float*)d_out;
  char* ws = (char*)d_ws;
  float* cosT = (float*)(ws);
  float* sinT = (float*)(ws + 1310720);
  float* a    = (float*)(ws + 2621440);
  unsigned short* wgp = (unsigned short*)(ws + 2934784);   // [288][296] bf16 = 170,496 B

  (void)hipFuncSetAttribute((const void*)k_out2,
                            hipFuncAttributeMaxDynamicSharedMemorySize, LDS_TOTAL);

  hipLaunchKernelGGL(k_trig,    dim3(1280),   dim3(256),  0, stream, loc, cosT, sinT);
  hipLaunchKernelGGL(k_agemm,   dim3(68, 5),  dim3(1024), 0, stream, zre, zim, cosT, sinT, a);
  hipLaunchKernelGGL(k_softmax, dim3(72),     dim3(256),  0, stream, a, wgp);
  hipLaunchKernelGGL(k_out2,    dim3(8, 128), dim3(1024), LDS_TOTAL, stream, X, wgp, out);
}